// Round 3
// baseline (551.419 us; speedup 1.0000x reference)
//
#include <hip/hip_runtime.h>
#include <hip/hip_bf16.h>
#include <stdint.h>

#define BATCH   2048
#define NIN     2048
#define NGATES  8192
#define NCOL    16384   // NGATES*2

typedef short s16x8 __attribute__((ext_vector_type(8)));   // 8 bf16 (4 VGPRs)
typedef float f32x4 __attribute__((ext_vector_type(4)));

__device__ __forceinline__ void gload_lds16(const void* g, void* l) {
  __builtin_amdgcn_global_load_lds(
      (const __attribute__((address_space(1))) void*)g,
      (__attribute__((address_space(3))) void*)l,
      16, 0, 0);
}

__device__ __forceinline__ unsigned short f2bf(float f) {
  __hip_bfloat16 h = __float2bfloat16(f);
  return __builtin_bit_cast(unsigned short, h);
}
__device__ __forceinline__ float bf2f(unsigned int u) {
  return __bfloat162float(__builtin_bit_cast(__hip_bfloat16,
                                             (unsigned short)(u & 0xffff)));
}

// ---------------------------------------------------------------------------
// Kernel 1: per-gate bilinear coefficients from softmax(w[:,g]).
// out = P0 + P1*A + P2*B + P3*A*B  (all 16 gates are bilinear in A,B)
// ---------------------------------------------------------------------------
__global__ __launch_bounds__(256) void gate_coeff_k(const float* __restrict__ w,
                                                    float4* __restrict__ coeff) {
  const int g = blockIdx.x * 256 + threadIdx.x;
  float e[16];
  float s = 0.f;
#pragma unroll
  for (int k = 0; k < 16; ++k) { e[k] = __expf(w[k * NGATES + g]); s += e[k]; }
  const float inv = 1.0f / s;
#pragma unroll
  for (int k = 0; k < 16; ++k) e[k] *= inv;
  const float P0 = e[8] + e[9] + e[10] + e[11] + e[12] + e[13] + e[14] + e[15];
  const float P1 = e[2] + e[3] + e[6] + e[7] - e[8] - e[9] - e[12] - e[13];
  const float P2 = e[4] + e[5] + e[6] + e[7] - e[8] - e[9] - e[10] - e[11];
  const float P3 = e[1] - e[2] - e[4] - 2.f * e[6] - e[7] + e[8] + 2.f * e[9]
                 + e[11] + e[13] - e[14];
  coeff[g] = make_float4(P0, P1, P2, P3);
}

// ---------------------------------------------------------------------------
// Kernel 2: x (fp32) -> bf16, row-major [B][K]
// ---------------------------------------------------------------------------
__global__ __launch_bounds__(256) void cvt_x_k(const float4* __restrict__ x,
                                               ushort4* __restrict__ xb) {
  const int i = blockIdx.x * 256 + threadIdx.x;
  float4 v = x[i];
  ushort4 h;
  h.x = f2bf(v.x); h.y = f2bf(v.y); h.z = f2bf(v.z); h.w = f2bf(v.w);
  xb[i] = h;
}

// ---------------------------------------------------------------------------
// Kernel 3: e = exp(c) bf16, transposed to bT[n][k]. BARRIER-FREE register
// transpose: each thread loads 8 rows x float4 (4 cols), exps, packs, and
// stores 4x16B k-contiguous chunks. Manual next-iter prefetch. Per-column
// partial sums of the bf16-rounded values reduced once through LDS at end.
// Grid: (NCOL/64, 4 row-quarters of 512). Block: 64 cols x 512 rows.
// ---------------------------------------------------------------------------
__global__ __launch_bounds__(256) void softmax_t_k(const float* __restrict__ c,
                                                   unsigned short* __restrict__ bT,
                                                   float* __restrict__ psums) {
  __shared__ float red[16][68];
  const int t = threadIdx.x;
  const int ng = (t & 15) * 4;   // 4 consecutive cols
  const int kg = t >> 4;         // 0..15: 8-row chunk
  const int n0 = blockIdx.x * 64;
  const int q  = blockIdx.y;
  const float* cb = c + (size_t)n0 + ng;
  float s0 = 0.f, s1 = 0.f, s2 = 0.f, s3 = 0.f;

  float4 v[8], nv[8];
  {
    const int r0 = q * 512 + kg * 8;
#pragma unroll
    for (int d = 0; d < 8; ++d)
      v[d] = *(const float4*)&cb[(size_t)(r0 + d) * NCOL];
  }
  for (int it = 0; it < 4; ++it) {
    if (it < 3) {
      const int r1 = q * 512 + (it + 1) * 128 + kg * 8;
#pragma unroll
      for (int d = 0; d < 8; ++d)
        nv[d] = *(const float4*)&cb[(size_t)(r1 + d) * NCOL];
    }
    unsigned int u[4][4];   // [col][k-pair]
#pragma unroll
    for (int d2 = 0; d2 < 4; ++d2) {
      float4 e0 = v[2 * d2], e1 = v[2 * d2 + 1];
      unsigned int a0 = f2bf(__expf(e0.x)), b0 = f2bf(__expf(e1.x));
      unsigned int a1 = f2bf(__expf(e0.y)), b1 = f2bf(__expf(e1.y));
      unsigned int a2 = f2bf(__expf(e0.z)), b2 = f2bf(__expf(e1.z));
      unsigned int a3 = f2bf(__expf(e0.w)), b3 = f2bf(__expf(e1.w));
      s0 += bf2f(a0) + bf2f(b0);
      s1 += bf2f(a1) + bf2f(b1);
      s2 += bf2f(a2) + bf2f(b2);
      s3 += bf2f(a3) + bf2f(b3);
      u[0][d2] = a0 | (b0 << 16);
      u[1][d2] = a1 | (b1 << 16);
      u[2][d2] = a2 | (b2 << 16);
      u[3][d2] = a3 | (b3 << 16);
    }
    const int i0 = q * 512 + it * 128 + kg * 8;
#pragma unroll
    for (int j = 0; j < 4; ++j) {
      uint4 pk = make_uint4(u[j][0], u[j][1], u[j][2], u[j][3]);
      *(uint4*)&bT[(size_t)(n0 + ng + j) * NIN + i0] = pk;
    }
    if (it < 3) {
#pragma unroll
      for (int d = 0; d < 8; ++d) v[d] = nv[d];
    }
  }
  red[kg][ng + 0] = s0;
  red[kg][ng + 1] = s1;
  red[kg][ng + 2] = s2;
  red[kg][ng + 3] = s3;
  __syncthreads();
  if (t < 64) {
    float tot = 0.f;
#pragma unroll
    for (int k2 = 0; k2 < 16; ++k2) tot += red[k2][t];
    psums[(size_t)q * NCOL + n0 + t] = tot;
  }
}

// ---------------------------------------------------------------------------
// Kernel 4: fold row-quarter partials -> invsum[n] = 1/sum
// ---------------------------------------------------------------------------
__global__ __launch_bounds__(256) void inv_k(const float* __restrict__ psums,
                                             float* __restrict__ invs) {
  const int n = blockIdx.x * 256 + threadIdx.x;
  invs[n] = 1.0f / (psums[n] + psums[NCOL + n] + psums[2 * NCOL + n] +
                    psums[3 * NCOL + n]);
}

// ---------------------------------------------------------------------------
// Kernel 5: bf16 MFMA GEMM, 128x128 tile, BK=32, 3-stage LDS pipeline with
// depth-2 prefetch: s_waitcnt vmcnt(4) (never 0 until the tail) so stage-k
// loads drain TWO compute phases after issue. XOR-swizzled LDS (rows paired
// into 128B lines, slot8 = (R&1)*4 + (q ^ ((R>>1)&3))) -> 2 lanes/slot on
// every ds_read_b128 = conflict-free. 48KB LDS -> 3 blocks/CU.
// ---------------------------------------------------------------------------
__global__ __launch_bounds__(256, 3) void gemm_gate_k(
    const unsigned short* __restrict__ xb,   // [2048][2048] bf16
    const unsigned short* __restrict__ bT,   // [16384][2048] bf16
    const float* __restrict__ invs,          // [16384]
    const float4* __restrict__ coeff,        // [8192]
    float* __restrict__ out) {               // [2048][8192]
  __shared__ __align__(16) char smem[49152]; // 3 stages x (A 8K + B 8K)
  float* outS = (float*)smem;

  const int t = threadIdx.x;
  const int l = t & 63;
  const int w = t >> 6;
  const int wm = w >> 1, wn = w & 1;

  // XCD-compact swizzle: per-XCD region = 16 n-tiles x 16 m-tiles
  const int bid = blockIdx.x;
  const int xcd = bid & 7, loc = bid >> 3;
  const int sup = loc >> 6, win = loc & 63;
  const int m0 = ((sup & 1) * 8 + (win & 7)) * 128;
  const int n0 = (xcd * 16 + (sup >> 1) * 8 + (win >> 3)) * 128;

  f32x4 acc[4][4] = {};

  // staging source map (inverse of the XOR swizzle, lane-order LDS placement)
  const int qk   = (t & 3) ^ ((t >> 3) & 3);        // 16B chunk within row
  const int rloc = 2 * (t >> 3) + ((t >> 2) & 1);   // row within 64-row group
  const unsigned short* gA0 = xb + (size_t)(m0 + rloc) * NIN + qk * 8;
  const unsigned short* gA1 = gA0 + (size_t)64 * NIN;
  const unsigned short* gB0 = bT + (size_t)(n0 + rloc) * NIN + qk * 8;
  const unsigned short* gB1 = gB0 + (size_t)64 * NIN;

  // fragment read offsets (slot8 constant across i/j register-tiles)
  const int fr = l & 15;
  const int cq = l >> 4;
  const int sl = (fr & 1) * 4 + (cq ^ ((fr >> 1) & 3));
  const int aoff = (32 * wm + (fr >> 1)) * 128 + sl * 16;
  const int boff = 8192 + (32 * wn + (fr >> 1)) * 128 + sl * 16;

  auto issue = [&](int stage, int kb) {
    char* dst = smem + stage * 16384 + t * 16;
    gload_lds16(gA0 + kb, dst);
    gload_lds16(gA1 + kb, dst + 4096);
    gload_lds16(gB0 + kb, dst + 8192);
    gload_lds16(gB1 + kb, dst + 12288);
  };
  auto compute = [&](const char* stb) {
    s16x8 af[4], bfr[4];
#pragma unroll
    for (int i = 0; i < 4; ++i)
      af[i] = *(const s16x8*)(stb + aoff + i * 1024);
#pragma unroll
    for (int j = 0; j < 4; ++j)
      bfr[j] = *(const s16x8*)(stb + boff + j * 1024);
#pragma unroll
    for (int i = 0; i < 4; ++i)
#pragma unroll
      for (int j = 0; j < 4; ++j)
        acc[i][j] = __builtin_amdgcn_mfma_f32_16x16x32_bf16(af[i], bfr[j],
                                                            acc[i][j], 0, 0, 0);
  };

  issue(0, 0);
  issue(1, 32);
  int sc = 0, si = 2;
  for (int kt = 0; kt < 63; ++kt) {
    // stage kt was issued 2 iters ago; leave the newer 4 loads in flight
    asm volatile("s_waitcnt vmcnt(4)\n\ts_barrier" ::: "memory");
    if (kt < 62) {
      issue(si, (kt + 2) * 32);
      si = (si == 2) ? 0 : si + 1;
    }
    compute(smem + sc * 16384);
    sc = (sc == 2) ? 0 : sc + 1;
  }
  asm volatile("s_waitcnt vmcnt(0)\n\ts_barrier" ::: "memory");
  compute(smem + sc * 16384);
  __syncthreads();

  // epilogue: normalize, pair even/odd columns (A,B), bilinear gate, store
  float  is4[4];
  float4 cf4[4];
  const int g0 = n0 >> 1;
#pragma unroll
  for (int j = 0; j < 4; ++j) {
    const int colg = n0 + 64 * wn + 16 * j + fr;
    is4[j] = invs[colg];
    cf4[j] = coeff[colg >> 1];
  }

  for (int half = 0; half < 2; ++half) {
    if (wm == half) {
#pragma unroll
      for (int i = 0; i < 4; ++i)
#pragma unroll
        for (int j = 0; j < 4; ++j)
#pragma unroll
          for (int r = 0; r < 4; ++r) {
            float v = acc[i][j][r] * is4[j];   // normalized y
            float o = __shfl_xor(v, 1);        // partner column
            if (!(l & 1)) {                    // even lane: col=2g -> A, o=B
              float A = v, B = o;
              float4 p = cf4[j];
              float res = p.x + p.y * A + p.z * B + p.w * A * B;
              const int row = 16 * i + ((l >> 4) << 2) + r;       // 0..63
              const int col = 32 * wn + 8 * j + (fr >> 1);        // 0..63
              outS[row * 68 + col] = res;
            }
          }
    }
    __syncthreads();
#pragma unroll
    for (int it = 0; it < 4; ++it) {
      const int row = it * 16 + (t >> 4);
      const int c4 = (t & 15) * 4;
      float4 vv = *(const float4*)&outS[row * 68 + c4];
      *(float4*)&out[(size_t)(m0 + half * 64 + row) * NGATES + g0 + c4] = vv;
    }
    __syncthreads();
  }
}

// ---------------------------------------------------------------------------
extern "C" void kernel_launch(void* const* d_in, const int* in_sizes, int n_in,
                              void* d_out, int out_size, void* d_ws,
                              size_t ws_size, hipStream_t stream) {
  const float* x = (const float*)d_in[0];   // [2048][2048]
  const float* w = (const float*)d_in[1];   // [16][8192]
  const float* c = (const float*)d_in[2];   // [2048][8192][2]
  float* out = (float*)d_out;               // [2048][8192]
  char* ws = (char*)d_ws;

  unsigned short* xb   = (unsigned short*)(ws);               // 8,388,608 B
  unsigned short* bT   = (unsigned short*)(ws + 8388608);     // 67,108,864 B
  float*          invs = (float*)(ws + 75497472);             // 65,536 B
  float4*         cf   = (float4*)(ws + 75563008);            // 131,072 B
  float*          ps   = (float*)(ws + 75694080);             // 262,144 B

  gate_coeff_k<<<NGATES / 256, 256, 0, stream>>>(w, cf);
  cvt_x_k<<<(BATCH * NIN / 4) / 256, 256, 0, stream>>>((const float4*)x,
                                                       (ushort4*)xb);
  dim3 sg(NCOL / 64, 4);
  softmax_t_k<<<sg, 256, 0, stream>>>(c, bT, ps);
  inv_k<<<NCOL / 256, 256, 0, stream>>>(ps, invs);
  gemm_gate_k<<<2048, 256, 0, stream>>>(xb, bT, invs, cf, out);
}

// Round 4
// 438.113 us; speedup vs baseline: 1.2586x; 1.2586x over previous
//
#include <hip/hip_runtime.h>
#include <hip/hip_bf16.h>
#include <stdint.h>

#define BATCH   2048
#define NIN     2048
#define NGATES  8192
#define NCOL    16384   // NGATES*2

typedef short s16x8 __attribute__((ext_vector_type(8)));   // 8 bf16 (4 VGPRs)
typedef float f32x4 __attribute__((ext_vector_type(4)));

__device__ __forceinline__ void gload_lds16(const void* g, void* l) {
  __builtin_amdgcn_global_load_lds(
      (const __attribute__((address_space(1))) void*)g,
      (__attribute__((address_space(3))) void*)l,
      16, 0, 0);
}

__device__ __forceinline__ unsigned short f2bf(float f) {
  __hip_bfloat16 h = __float2bfloat16(f);
  return __builtin_bit_cast(unsigned short, h);
}
__device__ __forceinline__ float bf2f(unsigned int u) {
  return __bfloat162float(__builtin_bit_cast(__hip_bfloat16,
                                             (unsigned short)(u & 0xffff)));
}

// ---------------------------------------------------------------------------
// Kernel 1: per-gate bilinear coefficients from softmax(w[:,g]).
// out = P0 + P1*A + P2*B + P3*A*B  (all 16 gates are bilinear in A,B)
// ---------------------------------------------------------------------------
__global__ __launch_bounds__(256) void gate_coeff_k(const float* __restrict__ w,
                                                    float4* __restrict__ coeff) {
  const int g = blockIdx.x * 256 + threadIdx.x;
  float e[16];
  float s = 0.f;
#pragma unroll
  for (int k = 0; k < 16; ++k) { e[k] = __expf(w[k * NGATES + g]); s += e[k]; }
  const float inv = 1.0f / s;
#pragma unroll
  for (int k = 0; k < 16; ++k) e[k] *= inv;
  const float P0 = e[8] + e[9] + e[10] + e[11] + e[12] + e[13] + e[14] + e[15];
  const float P1 = e[2] + e[3] + e[6] + e[7] - e[8] - e[9] - e[12] - e[13];
  const float P2 = e[4] + e[5] + e[6] + e[7] - e[8] - e[9] - e[10] - e[11];
  const float P3 = e[1] - e[2] - e[4] - 2.f * e[6] - e[7] + e[8] + 2.f * e[9]
                 + e[11] + e[13] - e[14];
  coeff[g] = make_float4(P0, P1, P2, P3);
}

// ---------------------------------------------------------------------------
// Kernel 2: x (fp32) -> bf16, row-major [B][K]
// ---------------------------------------------------------------------------
__global__ __launch_bounds__(256) void cvt_x_k(const float4* __restrict__ x,
                                               ushort4* __restrict__ xb) {
  const int i = blockIdx.x * 256 + threadIdx.x;
  float4 v = x[i];
  ushort4 h;
  h.x = f2bf(v.x); h.y = f2bf(v.y); h.z = f2bf(v.z); h.w = f2bf(v.w);
  xb[i] = h;
}

// ---------------------------------------------------------------------------
// Kernel 3: e = exp(c) bf16, transposed to bT[n][k]. Barrier-free register
// transpose; per-column partial sums of the bf16-rounded values.
// Grid: (NCOL/64, 4 row-quarters of 512).
// ---------------------------------------------------------------------------
__global__ __launch_bounds__(256) void softmax_t_k(const float* __restrict__ c,
                                                   unsigned short* __restrict__ bT,
                                                   float* __restrict__ psums) {
  __shared__ float red[16][68];
  const int t = threadIdx.x;
  const int ng = (t & 15) * 4;   // 4 consecutive cols
  const int kg = t >> 4;         // 0..15: 8-row chunk
  const int n0 = blockIdx.x * 64;
  const int q  = blockIdx.y;
  const float* cb = c + (size_t)n0 + ng;
  float s0 = 0.f, s1 = 0.f, s2 = 0.f, s3 = 0.f;

  float4 v[8], nv[8];
  {
    const int r0 = q * 512 + kg * 8;
#pragma unroll
    for (int d = 0; d < 8; ++d)
      v[d] = *(const float4*)&cb[(size_t)(r0 + d) * NCOL];
  }
  for (int it = 0; it < 4; ++it) {
    if (it < 3) {
      const int r1 = q * 512 + (it + 1) * 128 + kg * 8;
#pragma unroll
      for (int d = 0; d < 8; ++d)
        nv[d] = *(const float4*)&cb[(size_t)(r1 + d) * NCOL];
    }
    unsigned int u[4][4];   // [col][k-pair]
#pragma unroll
    for (int d2 = 0; d2 < 4; ++d2) {
      float4 e0 = v[2 * d2], e1 = v[2 * d2 + 1];
      unsigned int a0 = f2bf(__expf(e0.x)), b0 = f2bf(__expf(e1.x));
      unsigned int a1 = f2bf(__expf(e0.y)), b1 = f2bf(__expf(e1.y));
      unsigned int a2 = f2bf(__expf(e0.z)), b2 = f2bf(__expf(e1.z));
      unsigned int a3 = f2bf(__expf(e0.w)), b3 = f2bf(__expf(e1.w));
      s0 += bf2f(a0) + bf2f(b0);
      s1 += bf2f(a1) + bf2f(b1);
      s2 += bf2f(a2) + bf2f(b2);
      s3 += bf2f(a3) + bf2f(b3);
      u[0][d2] = a0 | (b0 << 16);
      u[1][d2] = a1 | (b1 << 16);
      u[2][d2] = a2 | (b2 << 16);
      u[3][d2] = a3 | (b3 << 16);
    }
    const int i0 = q * 512 + it * 128 + kg * 8;
#pragma unroll
    for (int j = 0; j < 4; ++j) {
      uint4 pk = make_uint4(u[j][0], u[j][1], u[j][2], u[j][3]);
      *(uint4*)&bT[(size_t)(n0 + ng + j) * NIN + i0] = pk;
    }
    if (it < 3) {
#pragma unroll
      for (int d = 0; d < 8; ++d) v[d] = nv[d];
    }
  }
  red[kg][ng + 0] = s0;
  red[kg][ng + 1] = s1;
  red[kg][ng + 2] = s2;
  red[kg][ng + 3] = s3;
  __syncthreads();
  if (t < 64) {
    float tot = 0.f;
#pragma unroll
    for (int k2 = 0; k2 < 16; ++k2) tot += red[k2][t];
    psums[(size_t)q * NCOL + n0 + t] = tot;
  }
}

// ---------------------------------------------------------------------------
// Kernel 4: fold row-quarter partials -> invsum[n] = 1/sum
// ---------------------------------------------------------------------------
__global__ __launch_bounds__(256) void inv_k(const float* __restrict__ psums,
                                             float* __restrict__ invs) {
  const int n = blockIdx.x * 256 + threadIdx.x;
  invs[n] = 1.0f / (psums[n] + psums[NCOL + n] + psums[2 * NCOL + n] +
                    psums[3 * NCOL + n]);
}

// ---------------------------------------------------------------------------
// Kernel 5: bf16 MFMA GEMM, 128x128 tile, BK=32, 4-stage LDS pipeline,
// prefetch depth 3: steady-state s_waitcnt vmcnt(8) so stage-k loads drain
// THREE compute phases after issue (covers HBM-miss ~900cyc). XOR-swizzled
// LDS (rows paired into 128B lines, slot8=(R&1)*4+(q^((R>>1)&3))) ->
// conflict-free ds_read_b128. launch_bounds(256,2): NO spills (r3 post-
// mortem: (256,3) forced VGPR->84 + 270MB scratch writes = regression).
// ---------------------------------------------------------------------------
__global__ __launch_bounds__(256, 2) void gemm_gate_k(
    const unsigned short* __restrict__ xb,   // [2048][2048] bf16
    const unsigned short* __restrict__ bT,   // [16384][2048] bf16
    const float* __restrict__ invs,          // [16384]
    const float4* __restrict__ coeff,        // [8192]
    float* __restrict__ out) {               // [2048][8192]
  __shared__ __align__(16) char smem[65536]; // 4 stages x (A 8K + B 8K)
  float* outS = (float*)smem;

  const int t = threadIdx.x;
  const int l = t & 63;
  const int w = t >> 6;
  const int wm = w >> 1, wn = w & 1;

  // XCD-compact swizzle: per-XCD region = 16 n-tiles x 16 m-tiles
  const int bid = blockIdx.x;
  const int xcd = bid & 7, loc = bid >> 3;
  const int sup = loc >> 6, win = loc & 63;
  const int m0 = ((sup & 1) * 8 + (win & 7)) * 128;
  const int n0 = (xcd * 16 + (sup >> 1) * 8 + (win >> 3)) * 128;

  f32x4 acc[4][4] = {};

  // staging source map (inverse of the XOR swizzle, lane-order LDS placement)
  const int qk   = (t & 3) ^ ((t >> 3) & 3);        // 16B chunk within row
  const int rloc = 2 * (t >> 3) + ((t >> 2) & 1);   // row within 64-row group
  const unsigned short* gA0 = xb + (size_t)(m0 + rloc) * NIN + qk * 8;
  const unsigned short* gA1 = gA0 + (size_t)64 * NIN;
  const unsigned short* gB0 = bT + (size_t)(n0 + rloc) * NIN + qk * 8;
  const unsigned short* gB1 = gB0 + (size_t)64 * NIN;

  // fragment read offsets (slot8 constant across i/j register-tiles)
  const int fr = l & 15;
  const int cq = l >> 4;
  const int sl = (fr & 1) * 4 + (cq ^ ((fr >> 1) & 3));
  const int aoff = (32 * wm + (fr >> 1)) * 128 + sl * 16;
  const int boff = 8192 + (32 * wn + (fr >> 1)) * 128 + sl * 16;

  auto issue = [&](int stage, int kb) {
    char* dst = smem + stage * 16384 + t * 16;
    gload_lds16(gA0 + kb, dst);
    gload_lds16(gA1 + kb, dst + 4096);
    gload_lds16(gB0 + kb, dst + 8192);
    gload_lds16(gB1 + kb, dst + 12288);
  };
  // pressure-reduced: 4 live B-frags, A-frags streamed one at a time
  auto compute = [&](const char* stb) {
    s16x8 bfr[4];
#pragma unroll
    for (int j = 0; j < 4; ++j)
      bfr[j] = *(const s16x8*)(stb + boff + j * 1024);
#pragma unroll
    for (int i = 0; i < 4; ++i) {
      s16x8 af = *(const s16x8*)(stb + aoff + i * 1024);
#pragma unroll
      for (int j = 0; j < 4; ++j)
        acc[i][j] = __builtin_amdgcn_mfma_f32_16x16x32_bf16(af, bfr[j],
                                                            acc[i][j], 0, 0, 0);
    }
  };

  issue(0, 0);
  issue(1, 32);
  issue(2, 64);
  for (int kt = 0; kt < 62; ++kt) {
    // stage kt issued 3 compute-phases ago; keep 8 newer loads in flight
    asm volatile("s_waitcnt vmcnt(8)\n\ts_barrier" ::: "memory");
    if (kt < 61) issue((kt + 3) & 3, (kt + 3) * 32);
    compute(smem + (kt & 3) * 16384);
  }
  asm volatile("s_waitcnt vmcnt(4)\n\ts_barrier" ::: "memory");
  compute(smem + (62 & 3) * 16384);
  asm volatile("s_waitcnt vmcnt(0)\n\ts_barrier" ::: "memory");
  compute(smem + (63 & 3) * 16384);
  __syncthreads();

  // epilogue: normalize, pair even/odd columns (A,B), bilinear gate, store
  float  is4[4];
  float4 cf4[4];
  const int g0 = n0 >> 1;
#pragma unroll
  for (int j = 0; j < 4; ++j) {
    const int colg = n0 + 64 * wn + 16 * j + fr;
    is4[j] = invs[colg];
    cf4[j] = coeff[colg >> 1];
  }

  for (int half = 0; half < 2; ++half) {
    if (wm == half) {
#pragma unroll
      for (int i = 0; i < 4; ++i)
#pragma unroll
        for (int j = 0; j < 4; ++j)
#pragma unroll
          for (int r = 0; r < 4; ++r) {
            float v = acc[i][j][r] * is4[j];   // normalized y
            float o = __shfl_xor(v, 1);        // partner column
            if (!(l & 1)) {                    // even lane: col=2g -> A, o=B
              float A = v, B = o;
              float4 p = cf4[j];
              float res = p.x + p.y * A + p.z * B + p.w * A * B;
              const int row = 16 * i + ((l >> 4) << 2) + r;       // 0..63
              const int col = 32 * wn + 8 * j + (fr >> 1);        // 0..63
              outS[row * 68 + col] = res;
            }
          }
    }
    __syncthreads();
#pragma unroll
    for (int it = 0; it < 4; ++it) {
      const int row = it * 16 + (t >> 4);
      const int c4 = (t & 15) * 4;
      float4 vv = *(const float4*)&outS[row * 68 + c4];
      *(float4*)&out[(size_t)(m0 + half * 64 + row) * NGATES + g0 + c4] = vv;
    }
    __syncthreads();
  }
}

// ---------------------------------------------------------------------------
extern "C" void kernel_launch(void* const* d_in, const int* in_sizes, int n_in,
                              void* d_out, int out_size, void* d_ws,
                              size_t ws_size, hipStream_t stream) {
  const float* x = (const float*)d_in[0];   // [2048][2048]
  const float* w = (const float*)d_in[1];   // [16][8192]
  const float* c = (const float*)d_in[2];   // [2048][8192][2]
  float* out = (float*)d_out;               // [2048][8192]
  char* ws = (char*)d_ws;

  unsigned short* xb   = (unsigned short*)(ws);               // 8,388,608 B
  unsigned short* bT   = (unsigned short*)(ws + 8388608);     // 67,108,864 B
  float*          invs = (float*)(ws + 75497472);             // 65,536 B
  float4*         cf   = (float4*)(ws + 75563008);            // 131,072 B
  float*          ps   = (float*)(ws + 75694080);             // 262,144 B

  gate_coeff_k<<<NGATES / 256, 256, 0, stream>>>(w, cf);
  cvt_x_k<<<(BATCH * NIN / 4) / 256, 256, 0, stream>>>((const float4*)x,
                                                       (ushort4*)xb);
  dim3 sg(NCOL / 64, 4);
  softmax_t_k<<<sg, 256, 0, stream>>>(c, bT, ps);
  inv_k<<<NCOL / 256, 256, 0, stream>>>(ps, invs);
  gemm_gate_k<<<2048, 256, 0, stream>>>(xb, bT, invs, cf, out);
}